// Round 18
// baseline (134.683 us; speedup 1.0000x reference)
//
#include <hip/hip_runtime.h>
#include <stdint.h>

typedef short short8 __attribute__((ext_vector_type(8)));
typedef short s16x4 __attribute__((ext_vector_type(4)));
typedef float f32x4 __attribute__((ext_vector_type(4)));

#define NB_H  1024
#define NB_NH 16
#define NB_HD 64
#define NB_B  8
#define NB_S  1024

__device__ __forceinline__ unsigned short f2bf(float f) {
    union { float f; unsigned u; } v; v.f = f;
    unsigned u = v.u;
    return (unsigned short)((u + 0x7fffu + ((u >> 16) & 1u)) >> 16);
}

__device__ __forceinline__ float exp2_fast(float x) {
    float r; asm("v_exp_f32 %0, %1" : "=v"(r) : "v"(x)); return r;
}

__device__ __forceinline__ void gload16(const void* g, void* l) {
    __builtin_amdgcn_global_load_lds(
        (const __attribute__((address_space(1))) void*)g,
        (__attribute__((address_space(3))) void*)l,
        16, 0, 0);
}

// ---------------------------------------------------------------- fused prologue
// blocks [0,3072): weights fp32->bf16 (3 x 1M elems)
// blocks [3072,11264): pos add + LayerNorm -> bf16 (8192 rows)
__global__ __launch_bounds__(256) void prologue_kernel(
    const float* __restrict__ wq, const float* __restrict__ wk, const float* __restrict__ wv,
    short* __restrict__ wbf,
    const float* __restrict__ hs, const float* __restrict__ pos,
    const float* __restrict__ lnw, const float* __restrict__ lnb,
    short* __restrict__ xbf)
{
    const int t = threadIdx.x;
    if (blockIdx.x < 3072) {
        unsigned i = (blockIdx.x * 256u + t) * 4u;  // total 3*1048576 elems
        const float* src = (i < (1u << 20)) ? wq : (i < (2u << 20)) ? wk : wv;
        const float4 v = *(const float4*)(src + (i & 0xFFFFFu));
        s16x4 o;
        o[0] = (short)f2bf(v.x); o[1] = (short)f2bf(v.y);
        o[2] = (short)f2bf(v.z); o[3] = (short)f2bf(v.w);
        *(s16x4*)(wbf + i) = o;
        return;
    }
    const int row = blockIdx.x - 3072;     // 0..8191 = b*1024 + s
    const int s   = row & 1023;
    const int wave = t >> 6, lane = t & 63;

    float4 x4 = *(const float4*)(hs  + (size_t)row * 1024 + t * 4);
    float4 p4 = *(const float4*)(pos + (size_t)s   * 1024 + t * 4);
    float v0 = x4.x + p4.x, v1 = x4.y + p4.y, v2 = x4.z + p4.z, v3 = x4.w + p4.w;

    float sum = v0 + v1 + v2 + v3;
    #pragma unroll
    for (int o = 1; o < 64; o <<= 1) sum += __shfl_xor(sum, o, 64);
    __shared__ float red[4];
    __shared__ float red2[4];
    if (lane == 0) red[wave] = sum;
    __syncthreads();
    float mu = (red[0] + red[1] + red[2] + red[3]) * (1.0f / 1024.0f);

    float d0 = v0 - mu, d1 = v1 - mu, d2 = v2 - mu, d3 = v3 - mu;
    float sq = d0 * d0 + d1 * d1 + d2 * d2 + d3 * d3;
    #pragma unroll
    for (int o = 1; o < 64; o <<= 1) sq += __shfl_xor(sq, o, 64);
    if (lane == 0) red2[wave] = sq;
    __syncthreads();
    float var = (red2[0] + red2[1] + red2[2] + red2[3]) * (1.0f / 1024.0f);
    float rs = rsqrtf(var + 1e-12f);

    const float4 w4 = *(const float4*)(lnw + t * 4);
    const float4 b4 = *(const float4*)(lnb + t * 4);
    s16x4 o;
    o[0] = (short)f2bf(d0 * rs * w4.x + b4.x);
    o[1] = (short)f2bf(d1 * rs * w4.y + b4.y);
    o[2] = (short)f2bf(d2 * rs * w4.z + b4.z);
    o[3] = (short)f2bf(d3 * rs * w4.w + b4.w);
    *(s16x4*)(xbf + (size_t)row * 1024 + t * 4) = o;
}

// ---------------------------------------------------------------- QKV GEMM
// BK=32 2-slot double-buffer with the attn-proven no-drain schedule:
// 32 steps of {vmcnt(4); barrier; compute(16 MFMA); barrier; stage(4 loads
// -> slot of kt+2)}. LDS 32 KB (4 blocks/CU — round 10 proved 64 KB/2-block
// dbuf loses; this keeps TLP AND removes the drain-to-0 stall of the
// 2-barrier version). 64B-row swizzle: scol=(chunk&3)^(row&3), read chunk
// l4^(row&3). All addresses hoisted. launch_bounds(256,4). T5 setprio.
// q pre-scaled by 0.125*log2(e); outputs q[bh][s][d], k[bh][s][d], vT[bh][d][s]
__global__ __launch_bounds__(256, 4) void qkv_gemm(
    const short* __restrict__ xbf,   // [8192][1024]
    const short* __restrict__ wbf,   // [3072][1024]
    const float* __restrict__ bq, const float* __restrict__ bk, const float* __restrict__ bv,
    short* __restrict__ q_bf, short* __restrict__ k_bf, short* __restrict__ vt_bf)
{
    __shared__ short lds_a[2][128 * 32];   // 2 x 8 KB, [row][4 chunks] XOR-swizzled
    __shared__ short lds_b[2][128 * 32];   // 2 x 8 KB  (total 32 KB)

    const int tid = threadIdx.x;
    const int wave = tid >> 6, lane = tid & 63;
    const int l15 = lane & 15, l4 = lane >> 4;
    const int m0 = blockIdx.x * 128;
    const int n0 = blockIdx.y * 128;
    const int wr = wave >> 1, wc = wave & 1;

    f32x4 acc[4][4] = {};

    // hoisted staging pointers (pre-swizzled source; advance +=32 per K-step)
    const short* pA[2];
    const short* pB[2];
    int ldsOff[2];
    #pragma unroll
    for (int i = 0; i < 2; ++i) {
        const int chunk = i * 256 + tid;          // 0..511 (16B chunks)
        const int srow = chunk >> 2;              // 0..127
        const int scol = (chunk & 3) ^ (srow & 3);
        pA[i] = xbf + (size_t)(m0 + srow) * 1024 + scol * 8;
        pB[i] = wbf + (size_t)(n0 + srow) * 1024 + scol * 8;
        ldsOff[i] = chunk * 8;
    }
    auto stage = [&](int sl) {
        #pragma unroll
        for (int i = 0; i < 2; ++i) {
            gload16(pA[i], &lds_a[sl][ldsOff[i]]);
            gload16(pB[i], &lds_b[sl][ldsOff[i]]);
            pA[i] += 32;
            pB[i] += 32;
        }
    };

    // hoisted, loop-invariant swizzled LDS read offsets (elements)
    int offA[4], offB[4];
    #pragma unroll
    for (int mi = 0; mi < 4; ++mi) {
        const int ar = wr * 64 + mi * 16 + l15;
        offA[mi] = ar * 32 + ((l4 ^ (ar & 3)) << 3);
        const int br = wc * 64 + mi * 16 + l15;
        offB[mi] = br * 32 + ((l4 ^ (br & 3)) << 3);
    }

    auto compute = [&](int sl) {
        short8 af[4], bfr[4];
        #pragma unroll
        for (int mi = 0; mi < 4; ++mi) af[mi] = *(const short8*)(&lds_a[sl][offA[mi]]);
        #pragma unroll
        for (int nj = 0; nj < 4; ++nj) bfr[nj] = *(const short8*)(&lds_b[sl][offB[nj]]);
        __builtin_amdgcn_s_setprio(1);
        #pragma unroll
        for (int mi = 0; mi < 4; ++mi)
            #pragma unroll
            for (int nj = 0; nj < 4; ++nj)
                acc[mi][nj] = __builtin_amdgcn_mfma_f32_16x16x32_bf16(af[mi], bfr[nj], acc[mi][nj], 0, 0, 0);
        __builtin_amdgcn_s_setprio(0);
    };

    // prologue: stage K-steps 0 and 1 (depth-2 in flight)
    stage(0);
    stage(1);

    #pragma unroll 1
    for (int kt = 0; kt < 30; ++kt) {
        asm volatile("s_waitcnt vmcnt(4)" ::: "memory");  // stage(kt) landed (mine)
        __builtin_amdgcn_s_barrier();                      // ... and everyone's (RAW)
        compute(kt & 1);
        __builtin_amdgcn_s_barrier();                      // all reads done (WAR), no drain
        stage(kt & 1);                                     // stage(kt+2) into freed slot
    }
    // kt = 30: stage(31) still in flight
    asm volatile("s_waitcnt vmcnt(4)" ::: "memory");
    __builtin_amdgcn_s_barrier();
    compute(0);
    // kt = 31: final drain
    asm volatile("s_waitcnt vmcnt(0)" ::: "memory");
    __builtin_amdgcn_s_barrier();
    compute(1);

    // epilogue: scatter to q/k/vT (vT merged to short4 stores)
    #pragma unroll
    for (int mi = 0; mi < 4; ++mi)
        #pragma unroll
        for (int nj = 0; nj < 4; ++nj) {
            const int n = n0 + wc * 64 + nj * 16 + l15;
            const int which = n >> 10;
            const int hh = (n >> 6) & 15, dd = n & 63, nn = n & 1023;
            const float bias = (which == 0) ? bq[nn] : (which == 1) ? bk[nn] : bv[nn];
            const int mbase = m0 + wr * 64 + mi * 16 + l4 * 4;
            const int bi = mbase >> 10, s0 = mbase & 1023;
            if (which == 2) {
                s16x4 hv4;
                #pragma unroll
                for (int r = 0; r < 4; ++r) hv4[r] = (short)f2bf(acc[mi][nj][r] + bias);
                *(s16x4*)(vt_bf + (size_t)((bi * 16 + hh) * 64 + dd) * 1024 + s0) = hv4;
            } else {
                #pragma unroll
                for (int r = 0; r < 4; ++r) {
                    float val = acc[mi][nj][r] + bias;
                    if (which == 0) val *= 0.18033688f;   // (1/8) * log2(e)
                    const short hv = (short)f2bf(val);
                    if (which == 0) q_bf[(size_t)((bi * 16 + hh) * 1024 + s0 + r) * 64 + dd] = hv;
                    else            k_bf[(size_t)((bi * 16 + hh) * 1024 + s0 + r) * 64 + dd] = hv;
                }
            }
        }
}

// ---------------------------------------------------------------- flash attention
// Round-16 exact (64.2 us, VGPR 76, no spill): QBLK=128, 2-buffer LDS ring
// (32 KB), depth-2 prefetch, counted vmcnt(4), raw s_barriers (no drain).
// launch_bounds stays (256,3) — raising the min-waves arg caps the register
// allocator (rounds 13/14 spilled). Round 17 (QBLK=64, grid 2048) regressed:
// occupancy rose but per-key staging work doubled. All addresses hoisted.
// Swapped QK^T -> lane-local log2 softmax (defer-max THR=8, per-lane
// partial lsum) -> PV via 16x16x16bf16_1k. T5 setprio.
__global__ __launch_bounds__(256, 3) void attn_kernel(
    const short* __restrict__ q_bf, const short* __restrict__ k_bf,
    const short* __restrict__ vt_bf, float* __restrict__ out)
{
    __shared__ short lds_k[2][64 * 64];   // [buf][key 64][d 64], 16B-chunk swizzled
    __shared__ short lds_v[2][64 * 64];   // [buf][d 64][key 64], 16B-chunk swizzled

    const int lin = blockIdx.x;
    const int xcd = lin & 7, kk = lin >> 3;
    const int bh = xcd * 16 + (kk & 15);
    const int qt = kk >> 4;
    const int bi = bh >> 4, hh = bh & 15;
    const int tid = threadIdx.x, wave = tid >> 6, lane = tid & 63;
    const int l15 = lane & 15, l4 = lane >> 4;
    const int qrow0 = qt * 128 + wave * 32;

    const short* qb = q_bf  + (size_t)bh * NB_S * NB_HD;
    const short* kb = k_bf  + (size_t)bh * NB_S * NB_HD;
    const short* vb = vt_bf + (size_t)bh * NB_HD * NB_S;

    // Q fragments (pre-scaled): Q[q=l15][d=ks*32+l4*8..]
    short8 qa[2][2];
    #pragma unroll
    for (int mi = 0; mi < 2; ++mi)
        #pragma unroll
        for (int ks = 0; ks < 2; ++ks)
            qa[mi][ks] = *(const short8*)(qb + (size_t)(qrow0 + mi * 16 + l15) * 64 + ks * 32 + l4 * 8);

    f32x4 oacc[2][4] = {};                // O^T: lane holds d=nj*16+l4*4+r, q=l15
    float mrun[2], lsum[2];
    mrun[0] = mrun[1] = -1e30f;
    lsum[0] = lsum[1] = 0.0f;             // per-lane partial (own 16 keys/iter)

    // hoisted staging pointers (pre-swizzled source; advance per tile)
    const short* pK[2];
    const short* pV[2];
    int ldsOff[2];
    #pragma unroll
    for (int c = 0; c < 2; ++c) {
        const int chunk = c * 256 + tid;
        const int row = chunk >> 3;
        const int scc = (chunk & 7) ^ (row & 7);
        pK[c] = kb + (size_t)row * 64 + scc * 8;     // += 4096 per tile
        pV[c] = vb + (size_t)row * 1024 + scc * 8;   // += 64 per tile
        ldsOff[c] = chunk * 8;
    }
    auto stage = [&](int sl) {
        #pragma unroll
        for (int c = 0; c < 2; ++c) {
            gload16(pK[c], &lds_k[0][0] + sl * 4096 + ldsOff[c]);
            gload16(pV[c], &lds_v[0][0] + sl * 4096 + ldsOff[c]);
            pK[c] += 4096;
            pV[c] += 64;
        }
    };

    // hoisted, loop-invariant swizzled LDS read offsets (elements)
    int koff[4][2], voff[4][4];
    #pragma unroll
    for (int kt = 0; kt < 4; ++kt) {
        #pragma unroll
        for (int ks = 0; ks < 2; ++ks) {
            const int r = kt * 16 + l15;
            koff[kt][ks] = r * 64 + (((ks * 4 + l4) ^ (r & 7)) << 3);
        }
        #pragma unroll
        for (int nj = 0; nj < 4; ++nj) {
            const int row = nj * 16 + l15;
            voff[nj][kt] = row * 64 + (((kt * 2 + (l4 >> 1)) ^ (row & 7)) << 3) + (l4 & 1) * 4;
        }
    }

    auto compute = [&](int bt) {
        const short* kbase = &lds_k[0][0] + bt * 4096;
        const short* vbase = &lds_v[0][0] + bt * 4096;

        short8 kf[4][2];
        #pragma unroll
        for (int kt = 0; kt < 4; ++kt)
            #pragma unroll
            for (int ks = 0; ks < 2; ++ks)
                kf[kt][ks] = *(const short8*)(kbase + koff[kt][ks]);

        // S^T = mfma(K, Q): lane holds key=kt*16+l4*4+rr, q=l15
        f32x4 sacc[2][4] = {};
        __builtin_amdgcn_s_setprio(1);
        #pragma unroll
        for (int mi = 0; mi < 2; ++mi)
            #pragma unroll
            for (int kt = 0; kt < 4; ++kt)
                #pragma unroll
                for (int ks = 0; ks < 2; ++ks)
                    sacc[mi][kt] = __builtin_amdgcn_mfma_f32_16x16x32_bf16(kf[kt][ks], qa[mi][ks], sacc[mi][kt], 0, 0, 0);
        __builtin_amdgcn_s_setprio(0);

        // V^T fragments: V^T[d=nj*16+l15][key=kt*16+l4*4..+3]
        s16x4 vf[4][4];
        #pragma unroll
        for (int nj = 0; nj < 4; ++nj)
            #pragma unroll
            for (int kt = 0; kt < 4; ++kt)
                vf[nj][kt] = *(const s16x4*)(vbase + voff[nj][kt]);

        // lane-local online softmax, log2 domain, defer-max (THR=8)
        s16x4 pa[2][4];
        #pragma unroll
        for (int mi = 0; mi < 2; ++mi) {
            // per-lane max, tree form
            float a0 = fmaxf(fmaxf(sacc[mi][0][0], sacc[mi][0][1]), fmaxf(sacc[mi][0][2], sacc[mi][0][3]));
            float a1 = fmaxf(fmaxf(sacc[mi][1][0], sacc[mi][1][1]), fmaxf(sacc[mi][1][2], sacc[mi][1][3]));
            float a2 = fmaxf(fmaxf(sacc[mi][2][0], sacc[mi][2][1]), fmaxf(sacc[mi][2][2], sacc[mi][2][3]));
            float a3 = fmaxf(fmaxf(sacc[mi][3][0], sacc[mi][3][1]), fmaxf(sacc[mi][3][2], sacc[mi][3][3]));
            float tm = fmaxf(fmaxf(a0, a1), fmaxf(a2, a3));
            // vote with per-lane tm (equivalent: all-lanes <=> all-rows);
            // row-reduce only on the rare slow path
            if (!__all(tm <= mrun[mi] + 8.0f)) {
                tm = fmaxf(tm, __shfl_xor(tm, 16, 64));
                tm = fmaxf(tm, __shfl_xor(tm, 32, 64));
                const float mnew = fmaxf(mrun[mi], tm);
                const float fac = exp2_fast(mrun[mi] - mnew);
                lsum[mi] *= fac;
                #pragma unroll
                for (int nj = 0; nj < 4; ++nj)
                    #pragma unroll
                    for (int r = 0; r < 4; ++r) oacc[mi][nj][r] *= fac;
                mrun[mi] = mnew;
            }
            const float mcur = mrun[mi];
            float rsum = 0.0f;
            #pragma unroll
            for (int kt = 0; kt < 4; ++kt) {
                float p0 = exp2_fast(sacc[mi][kt][0] - mcur);
                float p1 = exp2_fast(sacc[mi][kt][1] - mcur);
                float p2 = exp2_fast(sacc[mi][kt][2] - mcur);
                float p3 = exp2_fast(sacc[mi][kt][3] - mcur);
                rsum += (p0 + p1) + (p2 + p3);
                union { s16x4 v; unsigned u[2]; } pu;
                asm("v_cvt_pk_bf16_f32 %0, %1, %2" : "=v"(pu.u[0]) : "v"(p0), "v"(p1));
                asm("v_cvt_pk_bf16_f32 %0, %1, %2" : "=v"(pu.u[1]) : "v"(p2), "v"(p3));
                pa[mi][kt] = pu.v;
            }
            lsum[mi] += rsum;     // per-lane partial; reduced once at epilogue
        }

        // PV: O^T += V^T * P^T  (16x16x16)
        __builtin_amdgcn_s_setprio(1);
        #pragma unroll
        for (int nj = 0; nj < 4; ++nj)
            #pragma unroll
            for (int kt = 0; kt < 4; ++kt)
                #pragma unroll
                for (int mi = 0; mi < 2; ++mi)
                    oacc[mi][nj] = __builtin_amdgcn_mfma_f32_16x16x16bf16_1k(
                        vf[nj][kt], pa[mi][kt], oacc[mi][nj], 0, 0, 0);
        __builtin_amdgcn_s_setprio(0);
    };

    // prologue: stage tiles 0 and 1 (depth-2 in flight)
    stage(0);
    stage(1);

    #pragma unroll 1
    for (int t = 0; t < 14; ++t) {
        asm volatile("s_waitcnt vmcnt(4)" ::: "memory");  // stage(t) landed (mine)
        __builtin_amdgcn_s_barrier();                      // ... and everyone's (RAW)
        compute(t & 1);
        __builtin_amdgcn_s_barrier();                      // all reads done (WAR), no drain
        stage(t & 1);                                      // stage(t+2) into just-freed buf
    }
    // t = 14: stage(15) still in flight
    asm volatile("s_waitcnt vmcnt(4)" ::: "memory");
    __builtin_amdgcn_s_barrier();
    compute(0);
    // t = 15: final drain
    asm volatile("s_waitcnt vmcnt(0)" ::: "memory");
    __builtin_amdgcn_s_barrier();
    compute(1);

    // epilogue: single cross-lane lsum reduce + direct float4 stores
    #pragma unroll
    for (int mi = 0; mi < 2; ++mi) {
        float l = lsum[mi];
        l += __shfl_xor(l, 16, 64);
        l += __shfl_xor(l, 32, 64);
        const float inv = 1.0f / l;
        #pragma unroll
        for (int nj = 0; nj < 4; ++nj) {
            float4 v;
            v.x = oacc[mi][nj][0] * inv;
            v.y = oacc[mi][nj][1] * inv;
            v.z = oacc[mi][nj][2] * inv;
            v.w = oacc[mi][nj][3] * inv;
            *(float4*)(out + ((size_t)bi * 1024 + qrow0 + mi * 16 + l15) * 1024
                           + hh * 64 + nj * 16 + l4 * 4) = v;
        }
    }
}

extern "C" void kernel_launch(void* const* d_in, const int* in_sizes, int n_in,
                              void* d_out, int out_size, void* d_ws, size_t ws_size,
                              hipStream_t stream) {
    const float* hs  = (const float*)d_in[0];
    const float* pos = (const float*)d_in[1];
    const float* lnw = (const float*)d_in[2];
    const float* lnb = (const float*)d_in[3];
    const float* wq  = (const float*)d_in[4];
    const float* bq  = (const float*)d_in[5];
    const float* wk  = (const float*)d_in[6];
    const float* bk  = (const float*)d_in[7];
    const float* wv  = (const float*)d_in[8];
    const float* bv  = (const float*)d_in[9];
    float* out = (float*)d_out;

    char* ws = (char*)d_ws;
    short* wbf  = (short*)(ws);                                  // 6,291,456 B
    short* xbf  = (short*)(ws + 6291456);                        // 16,777,216 B
    short* qbf  = (short*)(ws + 6291456 + 16777216);             // 16,777,216 B
    short* kbf  = (short*)(ws + 6291456 + 2 * 16777216);         // 16,777,216 B
    short* vtbf = (short*)(ws + 6291456 + 3 * 16777216);         // 16,777,216 B

    prologue_kernel<<<dim3(11264), dim3(256), 0, stream>>>(
        wq, wk, wv, wbf, hs, pos, lnw, lnb, xbf);
    qkv_gemm<<<dim3(64, 24), dim3(256), 0, stream>>>(xbf, wbf, bq, bk, bv, qbf, kbf, vtbf);
    attn_kernel<<<dim3(1024), dim3(256), 0, stream>>>(qbf, kbf, vtbf, out);
}

// Round 19
// 122.104 us; speedup vs baseline: 1.1030x; 1.1030x over previous
//
#include <hip/hip_runtime.h>
#include <stdint.h>

typedef short short8 __attribute__((ext_vector_type(8)));
typedef short s16x4 __attribute__((ext_vector_type(4)));
typedef float f32x4 __attribute__((ext_vector_type(4)));

#define NB_H  1024
#define NB_NH 16
#define NB_HD 64
#define NB_B  8
#define NB_S  1024

__device__ __forceinline__ unsigned short f2bf(float f) {
    union { float f; unsigned u; } v; v.f = f;
    unsigned u = v.u;
    return (unsigned short)((u + 0x7fffu + ((u >> 16) & 1u)) >> 16);
}

__device__ __forceinline__ float exp2_fast(float x) {
    float r; asm("v_exp_f32 %0, %1" : "=v"(r) : "v"(x)); return r;
}

__device__ __forceinline__ void gload16(const void* g, void* l) {
    __builtin_amdgcn_global_load_lds(
        (const __attribute__((address_space(1))) void*)g,
        (__attribute__((address_space(3))) void*)l,
        16, 0, 0);
}

// ---------------------------------------------------------------- fused prologue
// blocks [0,3072): weights fp32->bf16 (3 x 1M elems)
// blocks [3072,11264): pos add + LayerNorm -> bf16 (8192 rows)
// ~5.8 TB/s effective — at the HBM roofline for its ~70 MB of traffic.
__global__ __launch_bounds__(256) void prologue_kernel(
    const float* __restrict__ wq, const float* __restrict__ wk, const float* __restrict__ wv,
    short* __restrict__ wbf,
    const float* __restrict__ hs, const float* __restrict__ pos,
    const float* __restrict__ lnw, const float* __restrict__ lnb,
    short* __restrict__ xbf)
{
    const int t = threadIdx.x;
    if (blockIdx.x < 3072) {
        unsigned i = (blockIdx.x * 256u + t) * 4u;  // total 3*1048576 elems
        const float* src = (i < (1u << 20)) ? wq : (i < (2u << 20)) ? wk : wv;
        const float4 v = *(const float4*)(src + (i & 0xFFFFFu));
        s16x4 o;
        o[0] = (short)f2bf(v.x); o[1] = (short)f2bf(v.y);
        o[2] = (short)f2bf(v.z); o[3] = (short)f2bf(v.w);
        *(s16x4*)(wbf + i) = o;
        return;
    }
    const int row = blockIdx.x - 3072;     // 0..8191 = b*1024 + s
    const int s   = row & 1023;
    const int wave = t >> 6, lane = t & 63;

    float4 x4 = *(const float4*)(hs  + (size_t)row * 1024 + t * 4);
    float4 p4 = *(const float4*)(pos + (size_t)s   * 1024 + t * 4);
    float v0 = x4.x + p4.x, v1 = x4.y + p4.y, v2 = x4.z + p4.z, v3 = x4.w + p4.w;

    float sum = v0 + v1 + v2 + v3;
    #pragma unroll
    for (int o = 1; o < 64; o <<= 1) sum += __shfl_xor(sum, o, 64);
    __shared__ float red[4];
    __shared__ float red2[4];
    if (lane == 0) red[wave] = sum;
    __syncthreads();
    float mu = (red[0] + red[1] + red[2] + red[3]) * (1.0f / 1024.0f);

    float d0 = v0 - mu, d1 = v1 - mu, d2 = v2 - mu, d3 = v3 - mu;
    float sq = d0 * d0 + d1 * d1 + d2 * d2 + d3 * d3;
    #pragma unroll
    for (int o = 1; o < 64; o <<= 1) sq += __shfl_xor(sq, o, 64);
    if (lane == 0) red2[wave] = sq;
    __syncthreads();
    float var = (red2[0] + red2[1] + red2[2] + red2[3]) * (1.0f / 1024.0f);
    float rs = rsqrtf(var + 1e-12f);

    const float4 w4 = *(const float4*)(lnw + t * 4);
    const float4 b4 = *(const float4*)(lnb + t * 4);
    s16x4 o;
    o[0] = (short)f2bf(d0 * rs * w4.x + b4.x);
    o[1] = (short)f2bf(d1 * rs * w4.y + b4.y);
    o[2] = (short)f2bf(d2 * rs * w4.z + b4.z);
    o[3] = (short)f2bf(d3 * rs * w4.w + b4.w);
    *(s16x4*)(xbf + (size_t)row * 1024 + t * 4) = o;
}

// ---------------------------------------------------------------- QKV GEMM
// Round-11 proven BEST (46.4 us = 1111 TF): 2-barrier / 32 KB / 4 blocks
// per CU, all address work hoisted out of the K-loop (global ptrs advance
// +=64, swizzled ds_read offsets loop-invariant). launch_bounds(256,4).
// T5 setprio on MFMA cluster. Round 18's BK=32 no-drain variant regressed
// (74 us: 4-slot swizzle brought back 6.3M bank conflicts, 2x barriers,
// half the MFMA per sync) — multi-block TLP already absorbs the drain (m114).
// q pre-scaled by 0.125*log2(e); outputs q[bh][s][d], k[bh][s][d], vT[bh][d][s]
__global__ __launch_bounds__(256, 4) void qkv_gemm(
    const short* __restrict__ xbf,   // [8192][1024]
    const short* __restrict__ wbf,   // [3072][1024]
    const float* __restrict__ bq, const float* __restrict__ bk, const float* __restrict__ bv,
    short* __restrict__ q_bf, short* __restrict__ k_bf, short* __restrict__ vt_bf)
{
    __shared__ short lds_a[128 * 64];   // 16 KB, [row][8 chunks] XOR-swizzled
    __shared__ short lds_b[128 * 64];   // 16 KB

    const int tid = threadIdx.x;
    const int wave = tid >> 6, lane = tid & 63;
    const int l15 = lane & 15, l4 = lane >> 4;
    const int m0 = blockIdx.x * 128;
    const int n0 = blockIdx.y * 128;
    const int wr = wave >> 1, wc = wave & 1;

    f32x4 acc[4][4] = {};

    // hoisted staging pointers (pre-swizzled source; advance +=64 per K-tile)
    const short* pA[4];
    const short* pB[4];
    short* ldsA[4];
    short* ldsB[4];
    #pragma unroll
    for (int i = 0; i < 4; ++i) {
        const int chunk = i * 256 + tid;
        const int srow = chunk >> 3;
        const int scol = (chunk & 7) ^ (srow & 7);
        pA[i] = xbf + (size_t)(m0 + srow) * 1024 + scol * 8;
        pB[i] = wbf + (size_t)(n0 + srow) * 1024 + scol * 8;
        ldsA[i] = lds_a + chunk * 8;
        ldsB[i] = lds_b + chunk * 8;
    }

    // hoisted, loop-invariant swizzled LDS read offsets (elements)
    int offA[2][4], offB[2][4];
    #pragma unroll
    for (int ks = 0; ks < 2; ++ks) {
        #pragma unroll
        for (int mi = 0; mi < 4; ++mi) {
            const int ar = wr * 64 + mi * 16 + l15;
            offA[ks][mi] = ar * 64 + (((ks * 4 + l4) ^ (ar & 7)) << 3);
            const int br = wc * 64 + mi * 16 + l15;
            offB[ks][mi] = br * 64 + (((ks * 4 + l4) ^ (br & 7)) << 3);
        }
    }

    #pragma unroll 1
    for (int kt = 0; kt < 16; ++kt) {
        __syncthreads();
        #pragma unroll
        for (int i = 0; i < 4; ++i) {
            gload16(pA[i], ldsA[i]);
            gload16(pB[i], ldsB[i]);
            pA[i] += 64;
            pB[i] += 64;
        }
        __syncthreads();
        #pragma unroll
        for (int ks = 0; ks < 2; ++ks) {
            short8 af[4], bfr[4];
            #pragma unroll
            for (int mi = 0; mi < 4; ++mi) af[mi] = *(const short8*)(lds_a + offA[ks][mi]);
            #pragma unroll
            for (int nj = 0; nj < 4; ++nj) bfr[nj] = *(const short8*)(lds_b + offB[ks][nj]);
            __builtin_amdgcn_s_setprio(1);
            #pragma unroll
            for (int mi = 0; mi < 4; ++mi)
                #pragma unroll
                for (int nj = 0; nj < 4; ++nj)
                    acc[mi][nj] = __builtin_amdgcn_mfma_f32_16x16x32_bf16(af[mi], bfr[nj], acc[mi][nj], 0, 0, 0);
            __builtin_amdgcn_s_setprio(0);
        }
    }

    // epilogue: scatter to q/k/vT (vT merged to short4 stores)
    #pragma unroll
    for (int mi = 0; mi < 4; ++mi)
        #pragma unroll
        for (int nj = 0; nj < 4; ++nj) {
            const int n = n0 + wc * 64 + nj * 16 + l15;
            const int which = n >> 10;
            const int hh = (n >> 6) & 15, dd = n & 63, nn = n & 1023;
            const float bias = (which == 0) ? bq[nn] : (which == 1) ? bk[nn] : bv[nn];
            const int mbase = m0 + wr * 64 + mi * 16 + l4 * 4;
            const int bi = mbase >> 10, s0 = mbase & 1023;
            if (which == 2) {
                s16x4 hv4;
                #pragma unroll
                for (int r = 0; r < 4; ++r) hv4[r] = (short)f2bf(acc[mi][nj][r] + bias);
                *(s16x4*)(vt_bf + (size_t)((bi * 16 + hh) * 64 + dd) * 1024 + s0) = hv4;
            } else {
                #pragma unroll
                for (int r = 0; r < 4; ++r) {
                    float val = acc[mi][nj][r] + bias;
                    if (which == 0) val *= 0.18033688f;   // (1/8) * log2(e)
                    const short hv = (short)f2bf(val);
                    if (which == 0) q_bf[(size_t)((bi * 16 + hh) * 1024 + s0 + r) * 64 + dd] = hv;
                    else            k_bf[(size_t)((bi * 16 + hh) * 1024 + s0 + r) * 64 + dd] = hv;
                }
            }
        }
}

// ---------------------------------------------------------------- flash attention
// Round-16 exact BEST (64.2 us, VGPR 76, no spill): QBLK=128, 2-buffer LDS
// ring (32 KB), depth-2 prefetch, counted vmcnt(4), raw s_barriers (no
// drain in main loop). launch_bounds stays (256,3) — raising the min-waves
// arg caps the register allocator (rounds 13/14 spilled at 4/5). Round 17
// (QBLK=64, grid 2048) regressed: occupancy rose but per-key staging work
// doubled. All addresses hoisted. Swapped QK^T -> lane-local log2 softmax
// (defer-max THR=8, per-lane partial lsum) -> PV via 16x16x16bf16_1k.
// T5 setprio.
__global__ __launch_bounds__(256, 3) void attn_kernel(
    const short* __restrict__ q_bf, const short* __restrict__ k_bf,
    const short* __restrict__ vt_bf, float* __restrict__ out)
{
    __shared__ short lds_k[2][64 * 64];   // [buf][key 64][d 64], 16B-chunk swizzled
    __shared__ short lds_v[2][64 * 64];   // [buf][d 64][key 64], 16B-chunk swizzled

    const int lin = blockIdx.x;
    const int xcd = lin & 7, kk = lin >> 3;
    const int bh = xcd * 16 + (kk & 15);
    const int qt = kk >> 4;
    const int bi = bh >> 4, hh = bh & 15;
    const int tid = threadIdx.x, wave = tid >> 6, lane = tid & 63;
    const int l15 = lane & 15, l4 = lane >> 4;
    const int qrow0 = qt * 128 + wave * 32;

    const short* qb = q_bf  + (size_t)bh * NB_S * NB_HD;
    const short* kb = k_bf  + (size_t)bh * NB_S * NB_HD;
    const short* vb = vt_bf + (size_t)bh * NB_HD * NB_S;

    // Q fragments (pre-scaled): Q[q=l15][d=ks*32+l4*8..]
    short8 qa[2][2];
    #pragma unroll
    for (int mi = 0; mi < 2; ++mi)
        #pragma unroll
        for (int ks = 0; ks < 2; ++ks)
            qa[mi][ks] = *(const short8*)(qb + (size_t)(qrow0 + mi * 16 + l15) * 64 + ks * 32 + l4 * 8);

    f32x4 oacc[2][4] = {};                // O^T: lane holds d=nj*16+l4*4+r, q=l15
    float mrun[2], lsum[2];
    mrun[0] = mrun[1] = -1e30f;
    lsum[0] = lsum[1] = 0.0f;             // per-lane partial (own 16 keys/iter)

    // hoisted staging pointers (pre-swizzled source; advance per tile)
    const short* pK[2];
    const short* pV[2];
    int ldsOff[2];
    #pragma unroll
    for (int c = 0; c < 2; ++c) {
        const int chunk = c * 256 + tid;
        const int row = chunk >> 3;
        const int scc = (chunk & 7) ^ (row & 7);
        pK[c] = kb + (size_t)row * 64 + scc * 8;     // += 4096 per tile
        pV[c] = vb + (size_t)row * 1024 + scc * 8;   // += 64 per tile
        ldsOff[c] = chunk * 8;
    }
    auto stage = [&](int sl) {
        #pragma unroll
        for (int c = 0; c < 2; ++c) {
            gload16(pK[c], &lds_k[0][0] + sl * 4096 + ldsOff[c]);
            gload16(pV[c], &lds_v[0][0] + sl * 4096 + ldsOff[c]);
            pK[c] += 4096;
            pV[c] += 64;
        }
    };

    // hoisted, loop-invariant swizzled LDS read offsets (elements)
    int koff[4][2], voff[4][4];
    #pragma unroll
    for (int kt = 0; kt < 4; ++kt) {
        #pragma unroll
        for (int ks = 0; ks < 2; ++ks) {
            const int r = kt * 16 + l15;
            koff[kt][ks] = r * 64 + (((ks * 4 + l4) ^ (r & 7)) << 3);
        }
        #pragma unroll
        for (int nj = 0; nj < 4; ++nj) {
            const int row = nj * 16 + l15;
            voff[nj][kt] = row * 64 + (((kt * 2 + (l4 >> 1)) ^ (row & 7)) << 3) + (l4 & 1) * 4;
        }
    }

    auto compute = [&](int bt) {
        const short* kbase = &lds_k[0][0] + bt * 4096;
        const short* vbase = &lds_v[0][0] + bt * 4096;

        short8 kf[4][2];
        #pragma unroll
        for (int kt = 0; kt < 4; ++kt)
            #pragma unroll
            for (int ks = 0; ks < 2; ++ks)
                kf[kt][ks] = *(const short8*)(kbase + koff[kt][ks]);

        // S^T = mfma(K, Q): lane holds key=kt*16+l4*4+rr, q=l15
        f32x4 sacc[2][4] = {};
        __builtin_amdgcn_s_setprio(1);
        #pragma unroll
        for (int mi = 0; mi < 2; ++mi)
            #pragma unroll
            for (int kt = 0; kt < 4; ++kt)
                #pragma unroll
                for (int ks = 0; ks < 2; ++ks)
                    sacc[mi][kt] = __builtin_amdgcn_mfma_f32_16x16x32_bf16(kf[kt][ks], qa[mi][ks], sacc[mi][kt], 0, 0, 0);
        __builtin_amdgcn_s_setprio(0);

        // V^T fragments: V^T[d=nj*16+l15][key=kt*16+l4*4..+3]
        s16x4 vf[4][4];
        #pragma unroll
        for (int nj = 0; nj < 4; ++nj)
            #pragma unroll
            for (int kt = 0; kt < 4; ++kt)
                vf[nj][kt] = *(const s16x4*)(vbase + voff[nj][kt]);

        // lane-local online softmax, log2 domain, defer-max (THR=8)
        s16x4 pa[2][4];
        #pragma unroll
        for (int mi = 0; mi < 2; ++mi) {
            // per-lane max, tree form
            float a0 = fmaxf(fmaxf(sacc[mi][0][0], sacc[mi][0][1]), fmaxf(sacc[mi][0][2], sacc[mi][0][3]));
            float a1 = fmaxf(fmaxf(sacc[mi][1][0], sacc[mi][1][1]), fmaxf(sacc[mi][1][2], sacc[mi][1][3]));
            float a2 = fmaxf(fmaxf(sacc[mi][2][0], sacc[mi][2][1]), fmaxf(sacc[mi][2][2], sacc[mi][2][3]));
            float a3 = fmaxf(fmaxf(sacc[mi][3][0], sacc[mi][3][1]), fmaxf(sacc[mi][3][2], sacc[mi][3][3]));
            float tm = fmaxf(fmaxf(a0, a1), fmaxf(a2, a3));
            // vote with per-lane tm (equivalent: all-lanes <=> all-rows);
            // row-reduce only on the rare slow path
            if (!__all(tm <= mrun[mi] + 8.0f)) {
                tm = fmaxf(tm, __shfl_xor(tm, 16, 64));
                tm = fmaxf(tm, __shfl_xor(tm, 32, 64));
                const float mnew = fmaxf(mrun[mi], tm);
                const float fac = exp2_fast(mrun[mi] - mnew);
                lsum[mi] *= fac;
                #pragma unroll
                for (int nj = 0; nj < 4; ++nj)
                    #pragma unroll
                    for (int r = 0; r < 4; ++r) oacc[mi][nj][r] *= fac;
                mrun[mi] = mnew;
            }
            const float mcur = mrun[mi];
            float rsum = 0.0f;
            #pragma unroll
            for (int kt = 0; kt < 4; ++kt) {
                float p0 = exp2_fast(sacc[mi][kt][0] - mcur);
                float p1 = exp2_fast(sacc[mi][kt][1] - mcur);
                float p2 = exp2_fast(sacc[mi][kt][2] - mcur);
                float p3 = exp2_fast(sacc[mi][kt][3] - mcur);
                rsum += (p0 + p1) + (p2 + p3);
                union { s16x4 v; unsigned u[2]; } pu;
                asm("v_cvt_pk_bf16_f32 %0, %1, %2" : "=v"(pu.u[0]) : "v"(p0), "v"(p1));
                asm("v_cvt_pk_bf16_f32 %0, %1, %2" : "=v"(pu.u[1]) : "v"(p2), "v"(p3));
                pa[mi][kt] = pu.v;
            }
            lsum[mi] += rsum;     // per-lane partial; reduced once at epilogue
        }

        // PV: O^T += V^T * P^T  (16x16x16)
        __builtin_amdgcn_s_setprio(1);
        #pragma unroll
        for (int nj = 0; nj < 4; ++nj)
            #pragma unroll
            for (int kt = 0; kt < 4; ++kt)
                #pragma unroll
                for (int mi = 0; mi < 2; ++mi)
                    oacc[mi][nj] = __builtin_amdgcn_mfma_f32_16x16x16bf16_1k(
                        vf[nj][kt], pa[mi][kt], oacc[mi][nj], 0, 0, 0);
        __builtin_amdgcn_s_setprio(0);
    };

    // prologue: stage tiles 0 and 1 (depth-2 in flight)
    stage(0);
    stage(1);

    #pragma unroll 1
    for (int t = 0; t < 14; ++t) {
        asm volatile("s_waitcnt vmcnt(4)" ::: "memory");  // stage(t) landed (mine)
        __builtin_amdgcn_s_barrier();                      // ... and everyone's (RAW)
        compute(t & 1);
        __builtin_amdgcn_s_barrier();                      // all reads done (WAR), no drain
        stage(t & 1);                                      // stage(t+2) into just-freed buf
    }
    // t = 14: stage(15) still in flight
    asm volatile("s_waitcnt vmcnt(4)" ::: "memory");
    __builtin_amdgcn_s_barrier();
    compute(0);
    // t = 15: final drain
    asm volatile("s_waitcnt vmcnt(0)" ::: "memory");
    __builtin_amdgcn_s_barrier();
    compute(1);

    // epilogue: single cross-lane lsum reduce + direct float4 stores
    #pragma unroll
    for (int mi = 0; mi < 2; ++mi) {
        float l = lsum[mi];
        l += __shfl_xor(l, 16, 64);
        l += __shfl_xor(l, 32, 64);
        const float inv = 1.0f / l;
        #pragma unroll
        for (int nj = 0; nj < 4; ++nj) {
            float4 v;
            v.x = oacc[mi][nj][0] * inv;
            v.y = oacc[mi][nj][1] * inv;
            v.z = oacc[mi][nj][2] * inv;
            v.w = oacc[mi][nj][3] * inv;
            *(float4*)(out + ((size_t)bi * 1024 + qrow0 + mi * 16 + l15) * 1024
                           + hh * 64 + nj * 16 + l4 * 4) = v;
        }
    }
}

extern "C" void kernel_launch(void* const* d_in, const int* in_sizes, int n_in,
                              void* d_out, int out_size, void* d_ws, size_t ws_size,
                              hipStream_t stream) {
    const float* hs  = (const float*)d_in[0];
    const float* pos = (const float*)d_in[1];
    const float* lnw = (const float*)d_in[2];
    const float* lnb = (const float*)d_in[3];
    const float* wq  = (const float*)d_in[4];
    const float* bq  = (const float*)d_in[5];
    const float* wk  = (const float*)d_in[6];
    const float* bk  = (const float*)d_in[7];
    const float* wv  = (const float*)d_in[8];
    const float* bv  = (const float*)d_in[9];
    float* out = (float*)d_out;

    char* ws = (char*)d_ws;
    short* wbf  = (short*)(ws);                                  // 6,291,456 B
    short* xbf  = (short*)(ws + 6291456);                        // 16,777,216 B
    short* qbf  = (short*)(ws + 6291456 + 16777216);             // 16,777,216 B
    short* kbf  = (short*)(ws + 6291456 + 2 * 16777216);         // 16,777,216 B
    short* vtbf = (short*)(ws + 6291456 + 3 * 16777216);         // 16,777,216 B

    prologue_kernel<<<dim3(11264), dim3(256), 0, stream>>>(
        wq, wk, wv, wbf, hs, pos, lnw, lnb, xbf);
    qkv_gemm<<<dim3(64, 24), dim3(256), 0, stream>>>(xbf, wbf, bq, bk, bv, qbf, kbf, vtbf);
    attn_kernel<<<dim3(1024), dim3(256), 0, stream>>>(qbf, kbf, vtbf, out);
}